// Round 1
// baseline (73.419 us; speedup 1.0000x reference)
//
#include <hip/hip_runtime.h>

#define NI 6
#define NM 3
#define NR 729          // 3^6 rules
#define PART_RULES 243  // rules per part (fixed m0 digit)
#define BLK_ELEMS 64    // elements per block (one per lane)
#define NPART 3         // one wave per m0 digit
#define NTHREADS (BLK_ELEMS * NPART)
#define BATCH 32768

__global__ __launch_bounds__(NTHREADS) void anfis_kernel(
    const float* __restrict__ x,
    const float* __restrict__ centers,
    const float* __restrict__ sigmas,
    const float* __restrict__ rw,
    float* __restrict__ out)
{
    // rule weights staged with stride 8 so each rule is two aligned float4s
    __shared__ float wlds[NR * 8];
    __shared__ float red_num[NPART - 1][BLK_ELEMS];
    __shared__ float red_den[NPART - 1][BLK_ELEMS];

    const int lx   = threadIdx.x;  // element lane
    const int part = threadIdx.y;  // 0..2 == value of digit m0 (one wave each)
    const int tid  = lx + BLK_ELEMS * part;

    // ---- stage rule weights into LDS ----
    for (int r = tid; r < NR; r += NTHREADS) {
        const float* src = rw + r * 7;
        float* dst = wlds + r * 8;
        #pragma unroll
        for (int j = 0; j < 7; ++j) dst[j] = src[j];
        dst[7] = 0.0f;
    }

    // ---- per-element membership functions (min-shifted: never underflows) ----
    const int elem = blockIdx.x * BLK_ELEMS + lx;
    const float* xp = x + elem * NI;
    float xv[NI];
    #pragma unroll
    for (int i = 0; i < NI; ++i) xv[i] = xp[i];

    float mf[NI][NM];
    #pragma unroll
    for (int i = 0; i < NI; ++i) {
        float z[NM];
        #pragma unroll
        for (int m = 0; m < NM; ++m) {
            const float t = (xv[i] - centers[i * NM + m]) *
                            __builtin_amdgcn_rcpf(sigmas[i * NM + m]);
            z[m] = t * t;
        }
        const float zmin = fminf(fminf(z[0], z[1]), z[2]);
        #pragma unroll
        for (int m = 0; m < NM; ++m)
            mf[i][m] = __expf(-0.5f * (z[m] - zmin));  // one of these is 1.0
    }

    __syncthreads();

    // ---- rule loop: this wave owns digit m0 == part (243 rules) ----
    float g45[9];
    #pragma unroll
    for (int m4 = 0; m4 < 3; ++m4)
        #pragma unroll
        for (int m5 = 0; m5 < 3; ++m5)
            g45[m4 * 3 + m5] = mf[4][m4] * mf[5][m5];

    const float a0 = mf[0][part];
    float num = 0.0f, den = 0.0f;
    int r = part * PART_RULES;
    for (int m1 = 0; m1 < 3; ++m1) {
        const float a1 = a0 * mf[1][m1];
        for (int m2 = 0; m2 < 3; ++m2) {
            const float a2 = a1 * mf[2][m2];
            #pragma unroll
            for (int m3 = 0; m3 < 3; ++m3) {
                const float a3 = a2 * mf[3][m3];
                #pragma unroll
                for (int k = 0; k < 9; ++k) {
                    const float s = a3 * g45[k];
                    const float4 wa = *reinterpret_cast<const float4*>(&wlds[(r + k) * 8]);
                    const float4 wb = *reinterpret_cast<const float4*>(&wlds[(r + k) * 8 + 4]);
                    float ro = wb.z;  // bias w[6]
                    ro = fmaf(xv[0], wa.x, ro);
                    ro = fmaf(xv[1], wa.y, ro);
                    ro = fmaf(xv[2], wa.z, ro);
                    ro = fmaf(xv[3], wa.w, ro);
                    ro = fmaf(xv[4], wb.x, ro);
                    ro = fmaf(xv[5], wb.y, ro);
                    num = fmaf(s, ro, num);
                    den += s;
                }
                r += 9;
            }
        }
    }

    // ---- cross-part reduction (3 waves -> wave 0) ----
    if (part != 0) {
        red_num[part - 1][lx] = num;
        red_den[part - 1][lx] = den;
    }
    __syncthreads();
    if (part == 0) {
        num += red_num[0][lx] + red_num[1][lx];
        den += red_den[0][lx] + red_den[1][lx];
        const float t = num * __builtin_amdgcn_rcpf(den);  // den >= 1 by min-shift
        const float e = __expf(-t);
        out[elem] = __builtin_amdgcn_rcpf(1.0f + e);
    }
}

extern "C" void kernel_launch(void* const* d_in, const int* in_sizes, int n_in,
                              void* d_out, int out_size, void* d_ws, size_t ws_size,
                              hipStream_t stream) {
    const float* x       = (const float*)d_in[0];
    const float* centers = (const float*)d_in[1];
    const float* sigmas  = (const float*)d_in[2];
    const float* rw      = (const float*)d_in[3];
    float* out           = (float*)d_out;

    dim3 block(BLK_ELEMS, NPART, 1);
    dim3 grid(BATCH / BLK_ELEMS, 1, 1);
    hipLaunchKernelGGL(anfis_kernel, grid, block, 0, stream,
                       x, centers, sigmas, rw, out);
}

// Round 2
// 71.230 us; speedup vs baseline: 1.0307x; 1.0307x over previous
//
#include <hip/hip_runtime.h>

#define NI 6
#define NM 3
#define NR 729          // 3^6 rules
#define NPART 9         // one wave per (m0,m1) digit pair
#define PART_RULES 81   // rules per wave
#define BLK_ELEMS 64    // elements per block (one per lane)
#define NTHREADS (BLK_ELEMS * NPART)  // 576
#define BATCH 32768

__global__ __launch_bounds__(NTHREADS) void anfis_kernel(
    const float* __restrict__ x,
    const float* __restrict__ centers,
    const float* __restrict__ sigmas,
    const float* __restrict__ rw,
    float* __restrict__ out)
{
    // rule weights staged with stride 8 so each rule is two aligned float4s
    __shared__ float wlds[NR * 8];
    __shared__ float red_num[NPART - 1][BLK_ELEMS];

    const int lx   = threadIdx.x;      // element lane (0..63)
    const int part = threadIdx.y;      // 0..8 == (m0,m1) pair, one wave each
    const int tid  = lx + BLK_ELEMS * part;
    const int m0   = part / 3;
    const int m1   = part % 3;

    // ---- stage rule weights into LDS (stride 8) ----
    for (int r = tid; r < NR; r += NTHREADS) {
        const float* src = rw + r * 7;
        float* dst = wlds + r * 8;
        #pragma unroll
        for (int j = 0; j < 7; ++j) dst[j] = src[j];
        dst[7] = 0.0f;
    }

    // ---- per-element membership functions (min-shifted: never all-underflow) ----
    const int elem = blockIdx.x * BLK_ELEMS + lx;
    const float* xp = x + elem * NI;
    float xv[NI];
    #pragma unroll
    for (int i = 0; i < NI; ++i) xv[i] = xp[i];

    float mf[NI][NM];
    #pragma unroll
    for (int i = 0; i < NI; ++i) {
        float z[NM];
        #pragma unroll
        for (int m = 0; m < NM; ++m) {
            const float t = (xv[i] - centers[i * NM + m]) *
                            __builtin_amdgcn_rcpf(sigmas[i * NM + m]);
            z[m] = t * t;
        }
        const float zmin = fminf(fminf(z[0], z[1]), z[2]);
        #pragma unroll
        for (int m = 0; m < NM; ++m)
            mf[i][m] = __expf(-0.5f * (z[m] - zmin));  // one of these is 1.0
    }

    __syncthreads();

    // ---- rule loop: this wave owns digits (m0,m1) == part (81 rules) ----
    float g45[9];
    #pragma unroll
    for (int m4 = 0; m4 < 3; ++m4)
        #pragma unroll
        for (int m5 = 0; m5 < 3; ++m5)
            g45[m4 * 3 + m5] = mf[4][m4] * mf[5][m5];

    const float a01 = mf[0][m0] * mf[1][m1];
    float num0 = 0.0f, num1 = 0.0f, num2 = 0.0f;  // break the FMA dep chain
    int r = part * PART_RULES;
    #pragma unroll
    for (int m2 = 0; m2 < 3; ++m2) {
        const float a2 = a01 * mf[2][m2];
        #pragma unroll
        for (int m3 = 0; m3 < 3; ++m3) {
            const float a3 = a2 * mf[3][m3];
            #pragma unroll
            for (int k = 0; k < 9; ++k) {
                const float s = a3 * g45[k];
                const float4 wa = *reinterpret_cast<const float4*>(&wlds[(r + k) * 8]);
                const float4 wb = *reinterpret_cast<const float4*>(&wlds[(r + k) * 8 + 4]);
                float ro = wb.z;  // bias w[6]
                ro = fmaf(xv[0], wa.x, ro);
                ro = fmaf(xv[1], wa.y, ro);
                ro = fmaf(xv[2], wa.z, ro);
                ro = fmaf(xv[3], wa.w, ro);
                ro = fmaf(xv[4], wb.x, ro);
                ro = fmaf(xv[5], wb.y, ro);
                if (k % 3 == 0)      num0 = fmaf(s, ro, num0);
                else if (k % 3 == 1) num1 = fmaf(s, ro, num1);
                else                 num2 = fmaf(s, ro, num2);
            }
            r += 9;
        }
    }
    const float num = (num0 + num1) + num2;

    // ---- cross-part reduction (9 waves -> wave 0) ----
    if (part != 0) red_num[part - 1][lx] = num;
    __syncthreads();
    if (part == 0) {
        float ntot = num;
        #pragma unroll
        for (int j = 0; j < NPART - 1; ++j) ntot += red_num[j][lx];
        // den is separable over inputs: sum over the full product grid factors
        float den = 1.0f;
        #pragma unroll
        for (int i = 0; i < NI; ++i)
            den *= (mf[i][0] + mf[i][1]) + mf[i][2];   // >= 1 by min-shift
        const float t = ntot * __builtin_amdgcn_rcpf(den);
        const float e = __expf(-t);
        out[elem] = __builtin_amdgcn_rcpf(1.0f + e);
    }
}

extern "C" void kernel_launch(void* const* d_in, const int* in_sizes, int n_in,
                              void* d_out, int out_size, void* d_ws, size_t ws_size,
                              hipStream_t stream) {
    const float* x       = (const float*)d_in[0];
    const float* centers = (const float*)d_in[1];
    const float* sigmas  = (const float*)d_in[2];
    const float* rw      = (const float*)d_in[3];
    float* out           = (float*)d_out;

    dim3 block(BLK_ELEMS, NPART, 1);
    dim3 grid(BATCH / BLK_ELEMS, 1, 1);
    hipLaunchKernelGGL(anfis_kernel, grid, block, 0, stream,
                       x, centers, sigmas, rw, out);
}